// Round 1
// baseline (1252.409 us; speedup 1.0000x reference)
//
#include <hip/hip_runtime.h>

typedef short  s16x8 __attribute__((ext_vector_type(8)));
typedef float  f32x4 __attribute__((ext_vector_type(4)));

#define NTOK   49
#define CDIM   384
#define NHEAD  12
#define HDIM   32
#define BWIN   4096

// ---- LDS element offsets (ushort/bf16 units) ----
// order matters: overflow fragment reads (rows 49..63) from attn_out/x/q/k land
// inside later buffers (garbage is provably discarded); p reads are in-bounds.
#define ATT_BASE 0              // [49][388]  attn concat output (bf16)
#define ATT_PITCH 388
#define X_BASE   19012          // [49][388]  x window (bf16)
#define Q_BASE   38024          // [4][49][40]  per-pass Q  [head][tok][hd]
#define K_BASE   45864          // [4][49][40]
#define V_BASE   53704          // [4][32][68]  per-pass V^T [head][hd][tok]
#define P_BASE   62408          // [4][64][68]  P  [head][query][key]
#define LDS_ELEMS 79816         // = 159632 bytes

// ws layout (bytes)
#define WS_COMB   0                       // [64][12][64][64] f32 = 12582912
#define WS_WQKV   12582912                // 1152*384 bf16 = 884736
#define WS_WP     (12582912 + 884736)     // 384*384 bf16 = 294912

#define MFMA(A,B,C) __builtin_amdgcn_mfma_f32_16x16x32_bf16(A,B,C,0,0,0)

__device__ __forceinline__ unsigned short f2bf(float f) {
    union { float f; unsigned int u; } v; v.f = f;
    unsigned int u = v.u;
    unsigned int r = (u + 0x7FFFu + ((u >> 16) & 1u)) >> 16;
    return (unsigned short)r;
}

__device__ __forceinline__ s16x8 lds_frag(const ushort* smem, int eidx) {
    union { unsigned long long q[2]; s16x8 v; } u;
    u.q[0] = *(const unsigned long long*)(smem + eidx);
    u.q[1] = *(const unsigned long long*)(smem + eidx + 4);
    return u.v;
}

__device__ __forceinline__ void lds_store4(ushort* smem, int eidx,
                                           float a, float b, float c, float d) {
    unsigned long long v = (unsigned long long)f2bf(a)
        | ((unsigned long long)f2bf(b) << 16)
        | ((unsigned long long)f2bf(c) << 32)
        | ((unsigned long long)f2bf(d) << 48);
    *(unsigned long long*)(smem + eidx) = v;
}

// ---------- prologue kernels (re-run every launch: ws is re-poisoned) ----------
__global__ void conv_weights(const float* __restrict__ qkv_w,
                             const float* __restrict__ proj_w,
                             ushort* __restrict__ wqkv, ushort* __restrict__ wp) {
    int i = blockIdx.x * 256 + threadIdx.x;           // grid covers 589824 exactly
    if (i < 1152*384) wqkv[i] = f2bf(qkv_w[i]);
    else              { int j = i - 1152*384; wp[j] = f2bf(proj_w[j]); }
}

__global__ void build_comb(const float* __restrict__ mask,
                           const float* __restrict__ table,
                           const int*   __restrict__ rel,
                           float* __restrict__ comb) {
    int idx = blockIdx.x * 256 + threadIdx.x;         // ((w*12+h)<<12) + (q<<6) + k
    int k = idx & 63, q = (idx >> 6) & 63;
    int wh = idx >> 12;
    int h = wh % 12, w = wh / 12;
    float v = 0.f;
    if (q < NTOK && k < NTOK)
        v = table[rel[q*NTOK + k]*NHEAD + h] + mask[w*(NTOK*NTOK) + q*NTOK + k];
    comb[idx] = v;
}

// ---------- fused window attention ----------
__global__ __launch_bounds__(512) void fused_attn(
        const float* __restrict__ x, const float* __restrict__ qkv_b,
        const float* __restrict__ proj_b,
        const ushort* __restrict__ wqkv, const ushort* __restrict__ wp,
        const float* __restrict__ comb, float* __restrict__ out) {
    extern __shared__ ushort smem[];
    const int tid  = threadIdx.x;
    const int bw   = blockIdx.x;
    const int wave = tid >> 6;
    const int lane = tid & 63;
    const int ln   = lane & 15;
    const int g    = lane >> 4;
    const int g8   = 8 * g;

    // ---- phase 0: stage x window -> bf16 LDS ----
    const float4* xg = (const float4*)(x + (size_t)bw * (NTOK*CDIM));
    for (int i = tid; i < NTOK*96; i += 512) {
        int r = i / 96, c4 = (i - r*96) * 4;
        float4 f = xg[i];
        lds_store4(smem, X_BASE + r*ATT_PITCH + c4, f.x, f.y, f.z, f.w);
    }
    __syncthreads();

    const float scale = 0.17677669529663687f;   // 1/sqrt(32)
    const int wg = bw & 63;

    for (int p = 0; p < 3; ++p) {
        // ---- QKV GEMM: wave handles Q-tile(wave), K-tile(wave), V-tile(wave);
        //      the three share the same x fragments each k-step.
        {
            const int hh = wave >> 1, dh = wave & 1;
            const int dimQ = (p*4 + hh)*HDIM + dh*16;
            const int dimK = 384 + dimQ;
            const int dimV = 768 + dimQ;
            const ushort* WQ = wqkv + (size_t)dimQ * CDIM;
            const ushort* WK = wqkv + (size_t)dimK * CDIM;
            const ushort* WV = wqkv + (size_t)dimV * CDIM;
            const int rowoff = ln*CDIM + g8;

            f32x4 accQ[4], accK[4], accV[4];
            #pragma unroll
            for (int t = 0; t < 4; ++t) {
                accQ[t] = (f32x4){0.f,0.f,0.f,0.f};
                accK[t] = (f32x4){0.f,0.f,0.f,0.f};
                accV[t] = (f32x4){0.f,0.f,0.f,0.f};
            }
            s16x8 fq = *(const s16x8*)(WQ + rowoff);
            s16x8 fk = *(const s16x8*)(WK + rowoff);
            s16x8 fv = *(const s16x8*)(WV + rowoff);
            #pragma unroll
            for (int ks = 0; ks < 12; ++ks) {
                const int k0 = ks * 32;
                const int kn = (ks < 11) ? k0 + 32 : k0;     // clamped prefetch
                s16x8 nq = *(const s16x8*)(WQ + rowoff + kn);
                s16x8 nk = *(const s16x8*)(WK + rowoff + kn);
                s16x8 nv = *(const s16x8*)(WV + rowoff + kn);
                s16x8 xa[4];
                #pragma unroll
                for (int nt = 0; nt < 4; ++nt)
                    xa[nt] = lds_frag(smem, X_BASE + (nt*16 + ln)*ATT_PITCH + k0 + g8);
                #pragma unroll
                for (int nt = 0; nt < 4; ++nt) {
                    accQ[nt] = MFMA(fq, xa[nt], accQ[nt]);   // D[dim][tok]
                    accK[nt] = MFMA(fk, xa[nt], accK[nt]);   // D[dim][tok]
                    accV[nt] = MFMA(xa[nt], fv, accV[nt]);   // D[tok][vdim]
                }
                fq = nq; fk = nk; fv = nv;
            }
            // epilogue Q/K: 4 regs = 4 consecutive dims at fixed tok (=col)
            float4 bq = *(const float4*)(qkv_b + dimQ + 4*g);
            float4 bk = *(const float4*)(qkv_b + dimK + 4*g);
            #pragma unroll
            for (int nt = 0; nt < 4; ++nt) {
                int tok = nt*16 + ln;
                if (tok < NTOK) {
                    lds_store4(smem, Q_BASE + hh*(NTOK*40) + tok*40 + dh*16 + 4*g,
                               accQ[nt].x + bq.x, accQ[nt].y + bq.y,
                               accQ[nt].z + bq.z, accQ[nt].w + bq.w);
                    lds_store4(smem, K_BASE + hh*(NTOK*40) + tok*40 + dh*16 + 4*g,
                               accK[nt].x + bk.x, accK[nt].y + bk.y,
                               accK[nt].z + bk.z, accK[nt].w + bk.w);
                }
            }
            // epilogue V^T: 4 regs = 4 consecutive toks at fixed vdim; pad toks -> 0
            float bv = qkv_b[dimV + ln];
            #pragma unroll
            for (int mt = 0; mt < 4; ++mt) {
                int tb = mt*16 + 4*g;
                float v0 = (tb+0 < NTOK) ? accV[mt].x + bv : 0.f;
                float v1 = (tb+1 < NTOK) ? accV[mt].y + bv : 0.f;
                float v2 = (tb+2 < NTOK) ? accV[mt].z + bv : 0.f;
                float v3 = (tb+3 < NTOK) ? accV[mt].w + bv : 0.f;
                lds_store4(smem, V_BASE + (hh*32 + dh*16 + ln)*68 + tb, v0, v1, v2, v3);
            }
        }
        __syncthreads();

        // ---- attention: wave -> head hh=wave>>1, query-half=wave&1 ----
        {
            const int hh = wave >> 1, half = wave & 1;
            const int h = p*4 + hh;
            // S^T[key][query] = sum_hd K[key][hd] * Q[query][hd]
            s16x8 aK[4], bQ[2];
            #pragma unroll
            for (int mt = 0; mt < 4; ++mt)
                aK[mt] = lds_frag(smem, K_BASE + hh*(NTOK*40) + (mt*16 + ln)*40 + g8);
            #pragma unroll
            for (int n2 = 0; n2 < 2; ++n2)
                bQ[n2] = lds_frag(smem, Q_BASE + hh*(NTOK*40) + ((half*2 + n2)*16 + ln)*40 + g8);
            f32x4 s[4][2];
            #pragma unroll
            for (int mt = 0; mt < 4; ++mt)
                #pragma unroll
                for (int n2 = 0; n2 < 2; ++n2) {
                    s[mt][n2] = (f32x4){0.f,0.f,0.f,0.f};
                    s[mt][n2] = MFMA(aK[mt], bQ[n2], s[mt][n2]);
                }

            const float* cbp = comb + (((size_t)wg*NHEAD + h) << 12);
            #pragma unroll
            for (int n2 = 0; n2 < 2; ++n2) {
                const int q = (half*2 + n2)*16 + ln;
                float mx = -3.0e38f;
                #pragma unroll
                for (int mt = 0; mt < 4; ++mt) {
                    int kb = mt*16 + 4*g;
                    float4 c4 = *(const float4*)(cbp + q*64 + kb);
                    float t0 = (kb+0 < NTOK) ? s[mt][n2].x*scale + c4.x : -3.0e38f;
                    float t1 = (kb+1 < NTOK) ? s[mt][n2].y*scale + c4.y : -3.0e38f;
                    float t2 = (kb+2 < NTOK) ? s[mt][n2].z*scale + c4.z : -3.0e38f;
                    float t3 = (kb+3 < NTOK) ? s[mt][n2].w*scale + c4.w : -3.0e38f;
                    s[mt][n2].x = t0; s[mt][n2].y = t1; s[mt][n2].z = t2; s[mt][n2].w = t3;
                    mx = fmaxf(mx, fmaxf(fmaxf(t0, t1), fmaxf(t2, t3)));
                }
                mx = fmaxf(mx, __shfl_xor(mx, 16));
                mx = fmaxf(mx, __shfl_xor(mx, 32));
                float sum = 0.f;
                #pragma unroll
                for (int mt = 0; mt < 4; ++mt) {
                    s[mt][n2].x = __expf(s[mt][n2].x - mx);
                    s[mt][n2].y = __expf(s[mt][n2].y - mx);
                    s[mt][n2].z = __expf(s[mt][n2].z - mx);
                    s[mt][n2].w = __expf(s[mt][n2].w - mx);
                    sum += s[mt][n2].x + s[mt][n2].y + s[mt][n2].z + s[mt][n2].w;
                }
                sum += __shfl_xor(sum, 16);
                sum += __shfl_xor(sum, 32);
                float inv = 1.0f / sum;
                #pragma unroll
                for (int mt = 0; mt < 4; ++mt)
                    lds_store4(smem, P_BASE + hh*4352 + q*68 + mt*16 + 4*g,
                               s[mt][n2].x*inv, s[mt][n2].y*inv,
                               s[mt][n2].z*inv, s[mt][n2].w*inv);
            }

            // O^T[d][q] = sum_s V^T[d][s] * P[q][s]   (wave reads only its own q rows)
            f32x4 o[2][2];
            #pragma unroll
            for (int a = 0; a < 2; ++a)
                #pragma unroll
                for (int b = 0; b < 2; ++b) o[a][b] = (f32x4){0.f,0.f,0.f,0.f};
            #pragma unroll
            for (int kst = 0; kst < 2; ++kst) {
                const int k0 = kst*32 + g8;
                s16x8 aV0 = lds_frag(smem, V_BASE + hh*2176 + (ln)*68 + k0);
                s16x8 aV1 = lds_frag(smem, V_BASE + hh*2176 + (16 + ln)*68 + k0);
                s16x8 bP0 = lds_frag(smem, P_BASE + hh*4352 + ((half*2+0)*16 + ln)*68 + k0);
                s16x8 bP1 = lds_frag(smem, P_BASE + hh*4352 + ((half*2+1)*16 + ln)*68 + k0);
                o[0][0] = MFMA(aV0, bP0, o[0][0]);
                o[0][1] = MFMA(aV0, bP1, o[0][1]);
                o[1][0] = MFMA(aV1, bP0, o[1][0]);
                o[1][1] = MFMA(aV1, bP1, o[1][1]);
            }
            #pragma unroll
            for (int mt2 = 0; mt2 < 2; ++mt2)
                #pragma unroll
                for (int n2 = 0; n2 < 2; ++n2) {
                    int q = (half*2 + n2)*16 + ln;
                    if (q < NTOK)
                        lds_store4(smem, ATT_BASE + q*ATT_PITCH + h*HDIM + mt2*16 + 4*g,
                                   o[mt2][n2].x, o[mt2][n2].y, o[mt2][n2].z, o[mt2][n2].w);
                }
        }
        __syncthreads();
    }

    // ---- proj: D[c][q] = sum_k Wp[c][k] * attn_out[q][k]; 3 c-tiles per wave ----
    #pragma unroll
    for (int jj = 0; jj < 3; ++jj) {
        const int ct = wave*3 + jj;
        const int cb = ct*16;
        const ushort* W = wp + (size_t)cb * CDIM;
        const int rowoff = ln*CDIM + g8;
        f32x4 acc[4];
        #pragma unroll
        for (int t = 0; t < 4; ++t) acc[t] = (f32x4){0.f,0.f,0.f,0.f};
        s16x8 fa = *(const s16x8*)(W + rowoff);
        #pragma unroll
        for (int ks = 0; ks < 12; ++ks) {
            const int k0 = ks*32;
            const int kn = (ks < 11) ? k0 + 32 : k0;
            s16x8 na = *(const s16x8*)(W + rowoff + kn);
            #pragma unroll
            for (int nt = 0; nt < 4; ++nt) {
                s16x8 bf_ = lds_frag(smem, ATT_BASE + (nt*16 + ln)*ATT_PITCH + k0 + g8);
                acc[nt] = MFMA(fa, bf_, acc[nt]);
            }
            fa = na;
        }
        float4 pb = *(const float4*)(proj_b + cb + 4*g);
        #pragma unroll
        for (int nt = 0; nt < 4; ++nt) {
            int q = nt*16 + ln;
            if (q < NTOK) {
                float4 ov;
                ov.x = acc[nt].x + pb.x; ov.y = acc[nt].y + pb.y;
                ov.z = acc[nt].z + pb.z; ov.w = acc[nt].w + pb.w;
                *(float4*)(out + ((size_t)bw*NTOK + q)*CDIM + cb + 4*g) = ov;
            }
        }
    }
}

extern "C" void kernel_launch(void* const* d_in, const int* in_sizes, int n_in,
                              void* d_out, int out_size, void* d_ws, size_t ws_size,
                              hipStream_t stream) {
    const float* x      = (const float*)d_in[0];
    const float* mask   = (const float*)d_in[1];
    const float* qkv_w  = (const float*)d_in[2];
    const float* qkv_b  = (const float*)d_in[3];
    const float* proj_w = (const float*)d_in[4];
    const float* proj_b = (const float*)d_in[5];
    const float* table  = (const float*)d_in[6];
    const int*   rel    = (const int*)d_in[7];
    float* out = (float*)d_out;

    float*  comb = (float*)((char*)d_ws + WS_COMB);
    ushort* wqkv = (ushort*)((char*)d_ws + WS_WQKV);
    ushort* wpb  = (ushort*)((char*)d_ws + WS_WP);

    hipLaunchKernelGGL(conv_weights, dim3(2304), dim3(256), 0, stream,
                       qkv_w, proj_w, wqkv, wpb);
    hipLaunchKernelGGL(build_comb, dim3(12288), dim3(256), 0, stream,
                       mask, table, rel, comb);

    hipFuncSetAttribute((const void*)fused_attn,
                        hipFuncAttributeMaxDynamicSharedMemorySize, 160*1024);
    hipLaunchKernelGGL(fused_attn, dim3(BWIN), dim3(512), LDS_ELEMS*2, stream,
                       x, qkv_b, proj_b, wqkv, wpb, comb, out);
}